// Round 4
// baseline (5943.557 us; speedup 1.0000x reference)
//
#include <hip/hip_runtime.h>

typedef unsigned short ushort_t;
typedef __bf16 bf16x8 __attribute__((ext_vector_type(8)));
typedef float f32x4 __attribute__((ext_vector_type(4)));
typedef unsigned int u32x4 __attribute__((ext_vector_type(4)));

#define T_STEPS 512
#define BATCH 64
#define HDIM 1024
#define CHUNK 32                 // steps per gate-precompute chunk
#define NCHUNK (T_STEPS / CHUNK) // 16
#define MCH (CHUNK * BATCH)      // 2048 rows per chunk GEMM
#define OUTS_ELEMS 33554432ULL
#define NWG 128                  // persistent WGs; <=1/CU, all co-resident

#define S_STRIDE 36              // padded fp32 row stride for S exchange

// ---- coherent (LLC-level, cross-XCD) access: sc0 sc1 bypass L1+L2 ----
// NOTE gfx950 modifier order: "off offset:N sc0 sc1" (imm offset BEFORE cache flags)
#define GLOADX4_COH_OFF(dst, base, OFF) \
    asm volatile("global_load_dwordx4 %0, %1, off offset:" #OFF " sc0 sc1" \
                 : "=v"(dst) : "v"(base) : "memory")
#define GLOAD16_CACHED(dst, src) \
    asm volatile("global_load_dwordx4 %0, %1, off" : "=v"(dst) : "v"(src) : "memory")
#define GSTORE16_COH(dst, val) \
    asm volatile("global_store_dwordx4 %0, %1, off sc0 sc1" :: "v"(dst), "v"(val) : "memory")
// raw workgroup barrier: LDS-visibility only, does NOT drain vmcnt
#define WGBAR() do { asm volatile("s_waitcnt lgkmcnt(0)" ::: "memory"); \
                     __builtin_amdgcn_s_barrier(); } while (0)

__device__ __forceinline__ ushort_t f2bf(float f) {
    union { unsigned int i; float f; } v;
    v.f = f;
    unsigned int x = v.i;
    unsigned int r = (x + 0x7FFFu + ((x >> 16) & 1u)) >> 16;
    return (ushort_t)r;
}

__device__ __forceinline__ float bf2f(ushort_t u) {
    union { unsigned int i; float f; } v;
    v.i = ((unsigned int)u) << 16;
    return v.f;
}

struct Ptr8 { const float* p[8]; };
struct Ptr4 { const float* p[4]; };

// ---------------------------------------------------------------------------
// Transpose+convert 8 fp32 weight matrices [1024 k][1024 n] -> bf16 [1024 n][1024 k]
// ---------------------------------------------------------------------------
__global__ __launch_bounds__(256) void transpose8(Ptr8 in, ushort_t* __restrict__ out) {
    __shared__ ushort_t tile[64][65];
    int z = blockIdx.z;
    const float* src = in.p[z];
    ushort_t* dst = out + (size_t)z * 1024 * 1024;
    int bx = blockIdx.x * 64;  // n base
    int by = blockIdx.y * 64;  // k base
    int t = threadIdx.x;
#pragma unroll
    for (int i = 0; i < 16; i++) {
        int lin = t + i * 256;
        int r = lin >> 6, c = lin & 63;
        tile[r][c] = f2bf(src[(size_t)(by + r) * 1024 + bx + c]);
    }
    __syncthreads();
#pragma unroll
    for (int i = 0; i < 16; i++) {
        int lin = t + i * 256;
        int r = lin >> 6, c = lin & 63;
        dst[(size_t)(bx + r) * 1024 + by + c] = tile[c][r];
    }
}

// ---------------------------------------------------------------------------
// Chunk GEMM: G[m][n'] = A[m][:] @ wt_x[n'][:] + bias   (fp32 acc, bf16 out)
// ---------------------------------------------------------------------------
#define BK 32
#define LDK 40

__global__ __launch_bounds__(256) void chunk_gemm(
    const float* __restrict__ A,
    const ushort_t* __restrict__ Wt,
    Ptr4 biases,
    ushort_t* __restrict__ G)            // [2048 m][4096 n']
{
    __shared__ ushort_t As[128 * LDK];
    __shared__ ushort_t Bs[128 * LDK];

    int n0 = blockIdx.x * 128;
    int m0 = blockIdx.y * 128;
    int t = threadIdx.x;
    int wave = t >> 6, lane = t & 63;
    int wm = (wave & 1) * 64, wn = (wave >> 1) * 64;
    int lrow = lane & 15, quad = lane >> 4;
    int lk = quad * 8;

    f32x4 acc[4][4] = {};

    for (int k0 = 0; k0 < 1024; k0 += BK) {
        __syncthreads();
#pragma unroll
        for (int i = 0; i < 4; i++) {
            int c = t + 256 * i;
            int r = c >> 3, kc = c & 7;
            const float4 v = *(const float4*)&A[(size_t)(m0 + r) * 1024 + k0 + kc * 4];
            ushort_t* d = &As[r * LDK + kc * 4];
            d[0] = f2bf(v.x); d[1] = f2bf(v.y); d[2] = f2bf(v.z); d[3] = f2bf(v.w);
        }
#pragma unroll
        for (int i = 0; i < 2; i++) {
            int c = t + 256 * i;
            int r = c >> 2, kc = c & 3;
            *(bf16x8*)&Bs[r * LDK + kc * 8] =
                *(const bf16x8*)&Wt[(size_t)(n0 + r) * 1024 + k0 + kc * 8];
        }
        __syncthreads();

        bf16x8 a[4], b[4];
#pragma unroll
        for (int i = 0; i < 4; i++)
            a[i] = *(const bf16x8*)&As[(wm + i * 16 + lrow) * LDK + lk];
#pragma unroll
        for (int j = 0; j < 4; j++)
            b[j] = *(const bf16x8*)&Bs[(wn + j * 16 + lrow) * LDK + lk];
#pragma unroll
        for (int i = 0; i < 4; i++)
#pragma unroll
            for (int j = 0; j < 4; j++)
                acc[i][j] = __builtin_amdgcn_mfma_f32_16x16x32_bf16(a[i], b[j], acc[i][j], 0, 0, 0);
    }

    int g = n0 >> 10;
    const float* bias = biases.p[g];
    int cg0 = (n0 & 1023) + wn;
#pragma unroll
    for (int j = 0; j < 4; j++) {
        int coln = n0 + wn + j * 16 + lrow;
        float bv = bias[cg0 + j * 16 + lrow];
#pragma unroll
        for (int i = 0; i < 4; i++) {
#pragma unroll
            for (int r = 0; r < 4; r++) {
                int rowm = m0 + wm + i * 16 + quad * 4 + r;
                G[(size_t)rowm * 4096 + coln] = f2bf(acc[i][j][r] + bv);
            }
        }
    }
}

// ---------------------------------------------------------------------------
// Init state + zero barrier flags (fresh per launch / graph replay)
// ---------------------------------------------------------------------------
__global__ __launch_bounds__(256) void init_state(
    const float* __restrict__ h0, const float* __restrict__ c0,
    float* __restrict__ hf, float* __restrict__ cf, ushort_t* __restrict__ hb,
    unsigned* __restrict__ flags)
{
    int i = blockIdx.x * 256 + threadIdx.x;  // 65536
    float h = h0[i];
    hf[i] = h;
    cf[i] = c0[i];
    hb[i] = f2bf(h);
    if (blockIdx.x == 0 && threadIdx.x < NWG) flags[threadIdx.x] = 0;
}

// ---------------------------------------------------------------------------
// Persistent per-chunk recurrence kernel — fully register-resident GEMM:
//   W fragments (B operand) loaded ONCE per chunk into 128 VGPRs.
//   h fragments (A operand) coherent-loaded DIRECTLY into MFMA registers
//   (waves partition batch-half x k-half disjointly -> no duplication).
//   No LDS in the GEMM path; LDS only for the S/gate exchange (23.5 KiB).
//   Per-slice counted vmcnt waits tie the consumed fragments (rule #18).
// ---------------------------------------------------------------------------
__global__ __launch_bounds__(256, 1) void lstm_chunk(
    const ushort_t* __restrict__ WtH,   // bf16 [4][1024 n][1024 k]
    const ushort_t* __restrict__ Gc,    // bf16 chunk gates [2048 m][4096 n']
    const float* __restrict__ ret,      // fp32 [1024]
    float* __restrict__ cf_g,           // fp32 chunk-boundary state
    float* __restrict__ hf_g,           // fp32 chunk-boundary state
    ushort_t* __restrict__ hb0,         // bf16 h ping
    ushort_t* __restrict__ hb1,         // bf16 h pong
    float* __restrict__ out,            // d_out fp32
    unsigned* __restrict__ flags,       // [NWG] barrier flags (monotonic)
    int c)                              // chunk index
{
    __shared__ float S[2 * 64 * S_STRIDE];   // kg-partial exchange, 18 KiB
    __shared__ ushort_t Gg[64 * 32];         // gate-precompute tile, 4 KiB
    __shared__ ushort_t Hw[512];             // gathered h-out tile, 1 KiB

    const int tid = threadIdx.x;
    const int wg = blockIdx.x;
    const int u0 = wg * 8;
    const int wave = tid >> 6, lane = tid & 63;
    const int lrow = lane & 15, quad = lane >> 4;
    const int mh = (wave & 1) * 32;     // batch-half base (rows)
    const int kg = wave >> 1;           // k-half (0/1): k = kg*512 + s*32 + quad*8

    // ---- W fragments: held in registers for the whole chunk (128 VGPRs) ----
    bf16x8 Bf0[16], Bf1[16];
    {
        const int kb = kg * 512 + quad * 8;
        const ushort_t* w0 = WtH + (size_t)(lrow >> 3) * 1048576
                                 + (size_t)(u0 + (lrow & 7)) * 1024 + kb;        // vc = lrow
        const ushort_t* w1 = WtH + (size_t)((16 + lrow) >> 3) * 1048576
                                 + (size_t)(u0 + (lrow & 7)) * 1024 + kb;        // vc = 16+lrow
#pragma unroll
        for (int s = 0; s < 16; s++) {
            Bf0[s] = *(const bf16x8*)(w0 + s * 32);
            Bf1[s] = *(const bf16x8*)(w1 + s * 32);
        }
    }

    // ---- persistent state in registers (2 (b,u) pairs per thread) ----
    float hf_r[2], cf_r[2], ret_r[2];
    int idx_r[2];
#pragma unroll
    for (int i = 0; i < 2; i++) {
        int lin = tid + i * 256;
        int b = lin >> 3, u = lin & 7;
        int idx = b * 1024 + u0 + u;
        idx_r[i] = idx;
        hf_r[i] = hf_g[idx];
        cf_r[i] = cf_g[idx];
        ret_r[i] = ret[u0 + u];
    }
    __syncthreads();
    // clean slate: no compiler-tracked VMEM outstanding when asm counting starts
    asm volatile("s_waitcnt vmcnt(0) lgkmcnt(0)" ::: "memory");

    const unsigned tbase = (unsigned)c * (unsigned)(CHUNK - 1);

#pragma unroll 1
    for (int tc = 0; tc < CHUNK; tc++) {
        const int t = c * CHUNK + tc;
        const ushort_t* hb_in = (tc & 1) ? hb1 : hb0;
        ushort_t* hb_out      = (tc & 1) ? hb0 : hb1;

        // gate-precompute prefetch — issued FIRST (oldest outstanding VM op)
        u32x4 gpre;
        {
            int b = tid >> 2, g = tid & 3;
            const ushort_t* gp = Gc + ((size_t)(tc * 64 + b)) * 4096 + g * 1024 + u0;
            GLOAD16_CACHED(gpre, gp);
        }

        // issue ALL 32 A-fragment coherent loads (16B each, direct to MFMA regs)
        u32x4 A0[16], A1[16];
        const ushort_t* pa0 = hb_in + (size_t)(mh + lrow) * 1024 + kg * 512 + quad * 8;
        const ushort_t* pa1 = pa0 + 16 * 1024;
#define ISS(s, OFF) GLOADX4_COH_OFF(A0[s], pa0, OFF); GLOADX4_COH_OFF(A1[s], pa1, OFF)
        ISS(0, 0);    ISS(1, 64);   ISS(2, 128);  ISS(3, 192);
        ISS(4, 256);  ISS(5, 320);  ISS(6, 384);  ISS(7, 448);
        ISS(8, 512);  ISS(9, 576);  ISS(10, 640); ISS(11, 704);
        ISS(12, 768); ISS(13, 832); ISS(14, 896); ISS(15, 960);
#undef ISS

        f32x4 acc[2][2] = {};
        // outstanding = 33 (gpre + 32). slice s needs first 2s+3 -> vmcnt(30-2s)
#define DO_SLICE(s, N) do { \
        asm volatile("s_waitcnt vmcnt(" #N ")" \
            : "+v"(A0[s]), "+v"(A1[s]) :: "memory"); \
        bf16x8 a0v = __builtin_bit_cast(bf16x8, A0[s]); \
        bf16x8 a1v = __builtin_bit_cast(bf16x8, A1[s]); \
        acc[0][0] = __builtin_amdgcn_mfma_f32_16x16x32_bf16(a0v, Bf0[s], acc[0][0], 0, 0, 0); \
        acc[0][1] = __builtin_amdgcn_mfma_f32_16x16x32_bf16(a0v, Bf1[s], acc[0][1], 0, 0, 0); \
        acc[1][0] = __builtin_amdgcn_mfma_f32_16x16x32_bf16(a1v, Bf0[s], acc[1][0], 0, 0, 0); \
        acc[1][1] = __builtin_amdgcn_mfma_f32_16x16x32_bf16(a1v, Bf1[s], acc[1][1], 0, 0, 0); \
    } while (0)
        // first slice also ties gpre (it completes first; ties prevent hoisting)
        do {
            asm volatile("s_waitcnt vmcnt(30)"
                : "+v"(A0[0]), "+v"(A1[0]), "+v"(gpre) :: "memory");
            bf16x8 a0v = __builtin_bit_cast(bf16x8, A0[0]);
            bf16x8 a1v = __builtin_bit_cast(bf16x8, A1[0]);
            acc[0][0] = __builtin_amdgcn_mfma_f32_16x16x32_bf16(a0v, Bf0[0], acc[0][0], 0, 0, 0);
            acc[0][1] = __builtin_amdgcn_mfma_f32_16x16x32_bf16(a0v, Bf1[0], acc[0][1], 0, 0, 0);
            acc[1][0] = __builtin_amdgcn_mfma_f32_16x16x32_bf16(a1v, Bf0[0], acc[1][0], 0, 0, 0);
            acc[1][1] = __builtin_amdgcn_mfma_f32_16x16x32_bf16(a1v, Bf1[0], acc[1][1], 0, 0, 0);
        } while (0);
        DO_SLICE(1, 28);  DO_SLICE(2, 26);  DO_SLICE(3, 24);
        DO_SLICE(4, 22);  DO_SLICE(5, 20);  DO_SLICE(6, 18);
        DO_SLICE(7, 16);  DO_SLICE(8, 14);  DO_SLICE(9, 12);
        DO_SLICE(10, 10); DO_SLICE(11, 8);  DO_SLICE(12, 6);
        DO_SLICE(13, 4);  DO_SLICE(14, 2);  DO_SLICE(15, 0);
#undef DO_SLICE

        // write kg-partial S (C/D layout: col = lane&15, row = quad*4 + r)
#pragma unroll
        for (int m = 0; m < 2; m++)
#pragma unroll
            for (int n = 0; n < 2; n++)
#pragma unroll
                for (int r = 0; r < 4; r++)
                    S[kg * 64 * S_STRIDE + (mh + m * 16 + quad * 4 + r) * S_STRIDE
                      + n * 16 + lrow] = acc[m][n][r];
        // park gate-precompute in LDS
        {
            int b = tid >> 2, g = tid & 3;
            *(u32x4*)&Gg[b * 32 + g * 8] = gpre;
        }
        WGBAR();

        // ---- elementwise LSTM + retention blend (register state) ----
        float hn_s[2];
#pragma unroll
        for (int i = 0; i < 2; i++) {
            int lin = tid + i * 256;
            int b = lin >> 3, u = lin & 7;
            int brow = b * S_STRIDE;
            float si = S[brow + u]      + S[64 * S_STRIDE + brow + u]      + bf2f(Gg[b * 32 + u]);
            float sf = S[brow + 8 + u]  + S[64 * S_STRIDE + brow + 8 + u]  + bf2f(Gg[b * 32 + 8 + u]);
            float so = S[brow + 16 + u] + S[64 * S_STRIDE + brow + 16 + u] + bf2f(Gg[b * 32 + 16 + u]);
            float sc = S[brow + 24 + u] + S[64 * S_STRIDE + brow + 24 + u] + bf2f(Gg[b * 32 + 24 + u]);
            float it = 1.f / (1.f + __expf(-si));
            float ft = 1.f / (1.f + __expf(-sf));
            float ot = 1.f / (1.f + __expf(-so));
            float gt = 1.f - 2.f / (__expf(2.f * sc) + 1.f);   // NaN-safe tanh
            float cn = cf_r[i] * ft + it * gt;
            float tcn = 1.f - 2.f / (__expf(2.f * cn) + 1.f);  // NaN-safe tanh
            float hl = ot * tcn;
            float rr = ret_r[i];
            float hn = rr * hf_r[i] + (1.f - rr) * hl;
            cf_r[i] = cn;
            hf_r[i] = hn;
            hn_s[i] = hn;
            Hw[lin] = f2bf(hn);                                // gather for coherent store
        }
        WGBAR();   // Hw visible

        // gathered coherent h-out store: wave 0 only (64 x 16B).
        // wave-level vmcnt(0) covers ALL 64 lanes' stores before tid0's flag.
        if (tid < 64) {
            u32x4 v = *(const u32x4*)&Hw[tid * 8];
            ushort_t* dst = hb_out + (size_t)tid * 1024 + u0;
            GSTORE16_COH(dst, v);
            asm volatile("s_waitcnt vmcnt(0)" ::: "memory");
        }
        if (tc < CHUNK - 1 && tid == 0)
            __hip_atomic_store(&flags[wg], tbase + (unsigned)tc + 1u,
                               __ATOMIC_RELAXED, __HIP_MEMORY_SCOPE_AGENT);

        // out NT stores AFTER the release path (off the flag's critical path)
#pragma unroll
        for (int i = 0; i < 2; i++)
            __builtin_nontemporal_store(hn_s[i], &out[(size_t)t * 65536 + idx_r[i]]);

        // ---- grid barrier between steps (skip after last) ----
        if (tc < CHUNK - 1) {
            unsigned target = tbase + (unsigned)tc + 1u;
            if (tid < NWG)
                while (__hip_atomic_load(&flags[tid], __ATOMIC_RELAXED,
                                         __HIP_MEMORY_SCOPE_AGENT) < target) {}
            WGBAR();
            asm volatile("s_waitcnt vmcnt(0)" ::: "memory");  // drain polls + NT stores
        }
    }

    // ---- write back chunk-boundary state ----
#pragma unroll
    for (int i = 0; i < 2; i++) {
        hf_g[idx_r[i]] = hf_r[i];
        cf_g[idx_r[i]] = cf_r[i];
    }
}

// ---------------------------------------------------------------------------
// Epilogue: append h_T and c_T (fp32) to d_out
// ---------------------------------------------------------------------------
__global__ __launch_bounds__(256) void epilogue_k(
    const float* __restrict__ hf_final, const float* __restrict__ cf,
    float* __restrict__ out)
{
    int i = blockIdx.x * 256 + threadIdx.x;  // 65536
    out[OUTS_ELEMS + i] = hf_final[i];
    out[OUTS_ELEMS + 65536 + i] = cf[i];
}

// ---------------------------------------------------------------------------
extern "C" void kernel_launch(void* const* d_in, const int* in_sizes, int n_in,
                              void* d_out, int out_size, void* d_ws, size_t ws_size,
                              hipStream_t stream)
{
    const float* input_ = (const float*)d_in[0];
    const float* h0   = (const float*)d_in[1];
    const float* c0   = (const float*)d_in[2];
    const float* w_xi = (const float*)d_in[3];
    const float* w_xf = (const float*)d_in[4];
    const float* w_xo = (const float*)d_in[5];
    const float* w_xc = (const float*)d_in[6];
    const float* w_hi = (const float*)d_in[7];
    const float* w_hf = (const float*)d_in[8];
    const float* w_ho = (const float*)d_in[9];
    const float* w_hc = (const float*)d_in[10];
    const float* b_i  = (const float*)d_in[11];
    const float* b_f  = (const float*)d_in[12];
    const float* b_o  = (const float*)d_in[13];
    const float* b_c  = (const float*)d_in[14];
    const float* ret  = (const float*)d_in[15];

    // workspace carve (~33.6 MiB)
    ushort_t* wt_x   = (ushort_t*)d_ws;            // 4*1M bf16  (8 MiB)
    ushort_t* wt_h   = wt_x + 4ULL * 1048576;      // 4*1M bf16  (8 MiB)
    ushort_t* gchunk = wt_h + 4ULL * 1048576;      // 2048*4096 bf16 (16 MiB)
    float*  cf  = (float*)(gchunk + (size_t)MCH * 4096);
    float*  hf0 = cf + 65536;
    float*  hf1 = hf0 + 65536;                     // (unused; carve kept stable)
    ushort_t* hb0 = (ushort_t*)(hf1 + 65536);
    ushort_t* hb1 = hb0 + 65536;
    unsigned* flags = (unsigned*)(hb1 + 65536);    // NWG barrier flags
    float* out = (float*)d_out;

    Ptr8 p8; p8.p[0] = w_xi; p8.p[1] = w_xf; p8.p[2] = w_xo; p8.p[3] = w_xc;
             p8.p[4] = w_hi; p8.p[5] = w_hf; p8.p[6] = w_ho; p8.p[7] = w_hc;
    transpose8<<<dim3(16, 16, 8), 256, 0, stream>>>(p8, wt_x);

    init_state<<<256, 256, 0, stream>>>(h0, c0, hf0, cf, hb0, flags);

    Ptr4 b4; b4.p[0] = b_i; b4.p[1] = b_f; b4.p[2] = b_o; b4.p[3] = b_c;

    for (int chunk = 0; chunk < NCHUNK; chunk++) {
        chunk_gemm<<<dim3(32, 16), 256, 0, stream>>>(
            input_ + (size_t)chunk * MCH * 1024, wt_x, b4, gchunk);
        lstm_chunk<<<NWG, 256, 0, stream>>>(
            wt_h, gchunk, ret, cf, hf0, hb0, hb1, out, flags, chunk);
    }

    epilogue_k<<<256, 256, 0, stream>>>(hf0, cf, out);
}